// Round 1
// baseline (509.143 us; speedup 1.0000x reference)
//
#include <hip/hip_runtime.h>

// ---------------------------------------------------------------------------
// Chamfer_Loss: chamfer(pred,tgt) + W_EDGE*edge + W_LAP*cotLap + W_NORMAL*nc
//               + W_VEL*chamfer(diff(pred), diff(tgt))
// B=2, N=8281 (g=91), fp32 in/out. Output: 1 scalar.
// ---------------------------------------------------------------------------

#define W_EDGE   0.5f
#define W_LAP    0.05f
#define W_NORMAL 0.01f
#define W_VEL    10.0f

__device__ __forceinline__ float wave_sum(float v) {
#pragma unroll
    for (int o = 32; o > 0; o >>= 1) v += __shfl_down(v, o, 64);
    return v;
}

// For each x point (possibly shifted diffs), min over all y points of squared
// distance. Partial mins over y-chunks combined via atomicMin on float bits
// (valid: all d >= 0, so IEEE bits are monotone as unsigned).
template<int SHIFT>
__global__ void chamfer_min_k(const float* __restrict__ X, const float* __restrict__ Y,
                              int N, unsigned int* __restrict__ outmin)
{
    const int Np = N - SHIFT;
    const int b  = blockIdx.z;
    const float* __restrict__ xb = X + (size_t)b * N * 3;
    const float* __restrict__ yb = Y + (size_t)b * N * 3;
    const int gx = blockIdx.x * blockDim.x + threadIdx.x;

    float x0 = 0.f, x1 = 0.f, x2 = 0.f;
    if (gx < Np) {
        if (SHIFT) {
            x0 = xb[(gx + 1) * 3 + 0] - xb[gx * 3 + 0];
            x1 = xb[(gx + 1) * 3 + 1] - xb[gx * 3 + 1];
            x2 = xb[(gx + 1) * 3 + 2] - xb[gx * 3 + 2];
        } else {
            x0 = xb[gx * 3 + 0]; x1 = xb[gx * 3 + 1]; x2 = xb[gx * 3 + 2];
        }
    }

    // y-chunk handled by this block
    const int nych = gridDim.y;
    const int per  = (Np + nych - 1) / nych;
    const int ys   = blockIdx.y * per;
    const int ye   = min(Np, ys + per);

    __shared__ float syx[256], syy[256], syz[256];

    float m = 3.0e38f;
    for (int t = ys; t < ye; t += 256) {
        const int cnt = min(256, ye - t);
        const int j = threadIdx.x;
        if (j < cnt) {
            const int yi = t + j;
            if (SHIFT) {
                syx[j] = yb[(yi + 1) * 3 + 0] - yb[yi * 3 + 0];
                syy[j] = yb[(yi + 1) * 3 + 1] - yb[yi * 3 + 1];
                syz[j] = yb[(yi + 1) * 3 + 2] - yb[yi * 3 + 2];
            } else {
                syx[j] = yb[yi * 3 + 0];
                syy[j] = yb[yi * 3 + 1];
                syz[j] = yb[yi * 3 + 2];
            }
        }
        __syncthreads();
#pragma unroll 8
        for (int jj = 0; jj < cnt; ++jj) {
            float dx = x0 - syx[jj];
            float dy = x1 - syy[jj];
            float dz = x2 - syz[jj];
            float d  = fmaf(dx, dx, fmaf(dy, dy, dz * dz));
            m = fminf(m, d);
        }
        __syncthreads();
    }
    if (gx < Np) atomicMin(&outmin[(size_t)b * Np + gx], __float_as_uint(m));
}

__global__ void reduce_sum_scaled_k(const float* __restrict__ v, int n, float scale,
                                    float* __restrict__ accum)
{
    float s = 0.f;
    for (int i = blockIdx.x * blockDim.x + threadIdx.x; i < n;
         i += gridDim.x * blockDim.x) s += v[i];
    s = wave_sum(s);
    if ((threadIdx.x & 63) == 0) atomicAdd(accum, s * scale);
}

__global__ void edge_loss_k(const float* __restrict__ pred, const int* __restrict__ edges,
                            int E, int N, int B, float scale, float* __restrict__ accum)
{
    float s = 0.f;
    const int total = B * E;
    for (int idx = blockIdx.x * blockDim.x + threadIdx.x; idx < total;
         idx += gridDim.x * blockDim.x) {
        const int b = idx / E;
        const int e = idx - b * E;
        const float* __restrict__ vb = pred + (size_t)b * N * 3;
        const int i0 = edges[e * 2 + 0], i1 = edges[e * 2 + 1];
        float dx = vb[i0 * 3 + 0] - vb[i1 * 3 + 0];
        float dy = vb[i0 * 3 + 1] - vb[i1 * 3 + 1];
        float dz = vb[i0 * 3 + 2] - vb[i1 * 3 + 2];
        s += fmaf(dx, dx, fmaf(dy, dy, dz * dz));
    }
    s = wave_sum(s);
    if ((threadIdx.x & 63) == 0) atomicAdd(accum, s * scale);
}

__global__ void lap_scatter_k(const float* __restrict__ pred, const int* __restrict__ faces,
                              int F, int N, int B,
                              float* __restrict__ Lx, float* __restrict__ rowsum)
{
    const int total = B * F;
    for (int idx = blockIdx.x * blockDim.x + threadIdx.x; idx < total;
         idx += gridDim.x * blockDim.x) {
        const int b = idx / F;
        const int f = idx - b * F;
        const float* __restrict__ vb = pred + (size_t)b * N * 3;
        const int i0 = faces[f * 3 + 0], i1 = faces[f * 3 + 1], i2 = faces[f * 3 + 2];
        float v0x = vb[i0 * 3], v0y = vb[i0 * 3 + 1], v0z = vb[i0 * 3 + 2];
        float v1x = vb[i1 * 3], v1y = vb[i1 * 3 + 1], v1z = vb[i1 * 3 + 2];
        float v2x = vb[i2 * 3], v2y = vb[i2 * 3 + 1], v2z = vb[i2 * 3 + 2];
        float ax = v1x - v2x, ay = v1y - v2y, az = v1z - v2z;
        float bx = v0x - v2x, by = v0y - v2y, bz = v0z - v2z;
        float cx = v0x - v1x, cy = v0y - v1y, cz = v0z - v1z;
        float A  = sqrtf(ax * ax + ay * ay + az * az);
        float Bl = sqrtf(bx * bx + by * by + bz * bz);
        float C  = sqrtf(cx * cx + cy * cy + cz * cz);
        float sp = 0.5f * (A + Bl + C);
        float area = sqrtf(fmaxf(sp * (sp - A) * (sp - Bl) * (sp - C), 1e-12f));
        float A2 = A * A, B2 = Bl * Bl, C2 = C * C;
        float inv4a = 1.0f / (4.0f * area);
        float cota = (B2 + C2 - A2) * inv4a;
        float cotb = (A2 + C2 - B2) * inv4a;
        float cotc = (A2 + B2 - C2) * inv4a;

        float* __restrict__ Lb = Lx + (size_t)b * N * 3;
        float* __restrict__ rb = rowsum + (size_t)b * N;
        // reference: cot[k] symmetric on edge (ii[k], jj[k]) with
        // ii=[1,2,0], jj=[2,0,1]: cota<->(1,2), cotb<->(2,0), cotc<->(0,1)
        #define SCAT(i, j, w)                                             \
            atomicAdd(&Lb[(i) * 3 + 0], (w) * vb[(j) * 3 + 0]);           \
            atomicAdd(&Lb[(i) * 3 + 1], (w) * vb[(j) * 3 + 1]);           \
            atomicAdd(&Lb[(i) * 3 + 2], (w) * vb[(j) * 3 + 2]);           \
            atomicAdd(&rb[(i)], (w));
        SCAT(i1, i2, cota) SCAT(i2, i1, cota)
        SCAT(i2, i0, cotb) SCAT(i0, i2, cotb)
        SCAT(i0, i1, cotc) SCAT(i1, i0, cotc)
        #undef SCAT
    }
}

__global__ void lap_final_k(const float* __restrict__ pred, const float* __restrict__ Lx,
                            const float* __restrict__ rowsum, int N, int B, float scale,
                            float* __restrict__ accum)
{
    float s = 0.f;
    const int total = B * N;
    for (int idx = blockIdx.x * blockDim.x + threadIdx.x; idx < total;
         idx += gridDim.x * blockDim.x) {
        float rs = rowsum[idx];
        float nw = rs > 0.f ? 1.0f / rs : 0.f;
        float rx = Lx[idx * 3 + 0] * nw - pred[idx * 3 + 0];
        float ry = Lx[idx * 3 + 1] * nw - pred[idx * 3 + 1];
        float rz = Lx[idx * 3 + 2] * nw - pred[idx * 3 + 2];
        s += sqrtf(rx * rx + ry * ry + rz * rz);
    }
    s = wave_sum(s);
    if ((threadIdx.x & 63) == 0) atomicAdd(accum, s * scale);
}

__global__ void nc_k(const float* __restrict__ pred, const int* __restrict__ pairs,
                     int P, int N, int B, float scale, float* __restrict__ accum)
{
    float s = 0.f;
    const int total = B * P;
    for (int idx = blockIdx.x * blockDim.x + threadIdx.x; idx < total;
         idx += gridDim.x * blockDim.x) {
        const int b = idx / P;
        const int p = idx - b * P;
        const float* __restrict__ vb = pred + (size_t)b * N * 3;
        const int a0 = pairs[p * 4 + 0], a1 = pairs[p * 4 + 1];
        const int a2 = pairs[p * 4 + 2], a3 = pairs[p * 4 + 3];
        float p0x = vb[a0 * 3], p0y = vb[a0 * 3 + 1], p0z = vb[a0 * 3 + 2];
        float p1x = vb[a1 * 3], p1y = vb[a1 * 3 + 1], p1z = vb[a1 * 3 + 2];
        float p2x = vb[a2 * 3], p2y = vb[a2 * 3 + 1], p2z = vb[a2 * 3 + 2];
        float p3x = vb[a3 * 3], p3y = vb[a3 * 3 + 1], p3z = vb[a3 * 3 + 2];
        float ex = p1x - p0x, ey = p1y - p0y, ez = p1z - p0z;
        float ux = p2x - p0x, uy = p2y - p0y, uz = p2z - p0z;
        float wx = p3x - p0x, wy = p3y - p0y, wz = p3z - p0z;
        // n0 = cross(e,u)
        float n0x = ey * uz - ez * uy;
        float n0y = ez * ux - ex * uz;
        float n0z = ex * uy - ey * ux;
        // n1 = -cross(e,w)
        float n1x = -(ey * wz - ez * wy);
        float n1y = -(ez * wx - ex * wz);
        float n1z = -(ex * wy - ey * wx);
        float dt = n0x * n1x + n0y * n1y + n0z * n1z;
        float l0 = sqrtf(n0x * n0x + n0y * n0y + n0z * n0z);
        float l1 = sqrtf(n1x * n1x + n1y * n1y + n1z * n1z);
        float cs = dt / (fmaxf(l0, 1e-8f) * fmaxf(l1, 1e-8f));
        s += 1.0f - cs;
    }
    s = wave_sum(s);
    if ((threadIdx.x & 63) == 0) atomicAdd(accum, s * scale);
}

__global__ void write_out_k(const float* __restrict__ accum, float* __restrict__ out)
{
    out[0] = accum[0];
}

extern "C" void kernel_launch(void* const* d_in, const int* in_sizes, int n_in,
                              void* d_out, int out_size, void* d_ws, size_t ws_size,
                              hipStream_t stream)
{
    const float* pred = (const float*)d_in[0];
    const float* tgt  = (const float*)d_in[1];
    const int* faces  = (const int*)d_in[2];
    const int* edges  = (const int*)d_in[3];
    const int* pairs  = (const int*)d_in[4];

    const int B = 2;
    const int N = in_sizes[0] / (3 * B);   // 8281
    const int F = in_sizes[2] / 3;         // 16200
    const int E = in_sizes[3] / 2;         // ~24480
    const int P = in_sizes[4] / 4;         // ~24120
    const int N1 = N - 1;

    // workspace layout (floats)
    float* ws       = (float*)d_ws;
    float* accum    = ws;                        // 8
    float* Lx       = ws + 8;                    // B*N*3
    float* rowsum   = Lx + (size_t)B * N * 3;    // B*N
    unsigned int* minA = (unsigned int*)(rowsum + (size_t)B * N); // B*N   pred->tgt
    unsigned int* minB = minA + (size_t)B * N;                    // B*N   tgt->pred
    unsigned int* minC = minB + (size_t)B * N;                    // B*N1  vel fwd
    unsigned int* minD = minC + (size_t)B * N1;                   // B*N1  vel bwd

    const size_t zero_bytes = (8 + (size_t)B * N * 3 + (size_t)B * N) * sizeof(float);
    const size_t inf_bytes  = (2 * (size_t)B * N + 2 * (size_t)B * N1) * sizeof(float);
    hipMemsetAsync(ws, 0, zero_bytes, stream);
    hipMemsetAsync(minA, 0x7F, inf_bytes, stream);  // 0x7F7F7F7F ~ 3.39e38 > any d

    const dim3 blk(256);
    const dim3 gc((N + 255) / 256, 8, B);
    const dim3 gv((N1 + 255) / 256, 8, B);
    chamfer_min_k<0><<<gc, blk, 0, stream>>>(pred, tgt, N, minA);
    chamfer_min_k<0><<<gc, blk, 0, stream>>>(tgt, pred, N, minB);
    chamfer_min_k<1><<<gv, blk, 0, stream>>>(pred, tgt, N, minC);
    chamfer_min_k<1><<<gv, blk, 0, stream>>>(tgt, pred, N, minD);

    const float sBN  = 1.0f / ((float)B * (float)N);
    const float sBN1 = W_VEL / ((float)B * (float)N1);
    reduce_sum_scaled_k<<<65, blk, 0, stream>>>((const float*)minA, B * N,  sBN,  accum);
    reduce_sum_scaled_k<<<65, blk, 0, stream>>>((const float*)minB, B * N,  sBN,  accum);
    reduce_sum_scaled_k<<<65, blk, 0, stream>>>((const float*)minC, B * N1, sBN1, accum);
    reduce_sum_scaled_k<<<65, blk, 0, stream>>>((const float*)minD, B * N1, sBN1, accum);

    edge_loss_k<<<96, blk, 0, stream>>>(pred, edges, E, N, B,
                                        W_EDGE / ((float)B * (float)E), accum);
    lap_scatter_k<<<128, blk, 0, stream>>>(pred, faces, F, N, B, Lx, rowsum);
    lap_final_k<<<65, blk, 0, stream>>>(pred, Lx, rowsum, N, B,
                                        W_LAP / ((float)B * (float)N), accum);
    nc_k<<<96, blk, 0, stream>>>(pred, pairs, P, N, B,
                                 W_NORMAL / ((float)B * (float)P), accum);

    write_out_k<<<1, 1, 0, stream>>>(accum, (float*)d_out);
}

// Round 2
// 161.857 us; speedup vs baseline: 3.1456x; 3.1456x over previous
//
#include <hip/hip_runtime.h>

// ---------------------------------------------------------------------------
// Chamfer_Loss: chamfer(pred,tgt) + W_EDGE*edge + W_LAP*cotLap + W_NORMAL*nc
//               + W_VEL*chamfer(diff(pred), diff(tgt))
// B=2, N=8281 (g=91), fp32 in/out. Output: 1 scalar.
// R2: register-tile x by NX=8 in chamfer (3 LDS reads amortized over 56 VALU
//     ops, 8 independent min chains), fuse small reductions.
// ---------------------------------------------------------------------------

#define W_EDGE   0.5f
#define W_LAP    0.05f
#define W_NORMAL 0.01f
#define W_VEL    10.0f

#define NX 8          // x points per thread (registers)
#define NYCH 52       // y chunks (grid.y)

__device__ __forceinline__ float wave_sum(float v) {
#pragma unroll
    for (int o = 32; o > 0; o >>= 1) v += __shfl_down(v, o, 64);
    return v;
}

// For each x point (possibly shifted diffs), min over all y points of squared
// distance. Partial mins over y-chunks combined via atomicMin on float bits
// (valid: all d >= 0, so IEEE bits are monotone as unsigned).
template<int SHIFT>
__global__ __launch_bounds__(256)
void chamfer_min_k(const float* __restrict__ X, const float* __restrict__ Y,
                   int N, unsigned int* __restrict__ outmin)
{
    const int Np = N - SHIFT;
    const int b  = blockIdx.z;
    const float* __restrict__ xb = X + (size_t)b * N * 3;
    const float* __restrict__ yb = Y + (size_t)b * N * 3;
    const int base = blockIdx.x * (256 * NX) + threadIdx.x;

    float xs0[NX], xs1[NX], xs2[NX], m[NX];
#pragma unroll
    for (int k = 0; k < NX; ++k) {
        const int gi = base + k * 256;
        m[k] = 3.0e38f;
        if (gi < Np) {
            if (SHIFT) {
                xs0[k] = xb[(gi + 1) * 3 + 0] - xb[gi * 3 + 0];
                xs1[k] = xb[(gi + 1) * 3 + 1] - xb[gi * 3 + 1];
                xs2[k] = xb[(gi + 1) * 3 + 2] - xb[gi * 3 + 2];
            } else {
                xs0[k] = xb[gi * 3 + 0];
                xs1[k] = xb[gi * 3 + 1];
                xs2[k] = xb[gi * 3 + 2];
            }
        } else {
            xs0[k] = 0.f; xs1[k] = 0.f; xs2[k] = 0.f;
        }
    }

    // y-range handled by this block
    const int per = (Np + gridDim.y - 1) / gridDim.y;
    const int ys  = blockIdx.y * per;
    const int ye  = min(Np, ys + per);

    __shared__ float syx[256], syy[256], syz[256];

    for (int t = ys; t < ye; t += 256) {
        const int cnt = min(256, ye - t);
        const int j = threadIdx.x;
        if (j < cnt) {
            const int yi = t + j;
            if (SHIFT) {
                syx[j] = yb[(yi + 1) * 3 + 0] - yb[yi * 3 + 0];
                syy[j] = yb[(yi + 1) * 3 + 1] - yb[yi * 3 + 1];
                syz[j] = yb[(yi + 1) * 3 + 2] - yb[yi * 3 + 2];
            } else {
                syx[j] = yb[yi * 3 + 0];
                syy[j] = yb[yi * 3 + 1];
                syz[j] = yb[yi * 3 + 2];
            }
        }
        __syncthreads();
#pragma unroll 4
        for (int jj = 0; jj < cnt; ++jj) {
            const float yx = syx[jj], yv = syy[jj], yz = syz[jj];
#pragma unroll
            for (int k = 0; k < NX; ++k) {
                float dx = xs0[k] - yx;
                float dy = xs1[k] - yv;
                float dz = xs2[k] - yz;
                float d  = fmaf(dx, dx, fmaf(dy, dy, dz * dz));
                m[k] = fminf(m[k], d);
            }
        }
        __syncthreads();
    }
#pragma unroll
    for (int k = 0; k < NX; ++k) {
        const int gi = base + k * 256;
        if (gi < Np) atomicMin(&outmin[(size_t)b * Np + gi], __float_as_uint(m[k]));
    }
}

// Sum all four min arrays (contiguous: [2*lenN @ scaleA][2*lenN1 @ scaleC]).
__global__ void reduce_mins_k(const unsigned int* __restrict__ mins, int lenN2, int lenN12,
                              float sA, float sC, float* __restrict__ accum)
{
    const int total = lenN2 + lenN12;
    float s = 0.f, s2 = 0.f;
    for (int i = blockIdx.x * blockDim.x + threadIdx.x; i < total;
         i += gridDim.x * blockDim.x) {
        const float v = __uint_as_float(mins[i]);
        if (i < lenN2) s += v; else s2 += v;
    }
    s  = wave_sum(s);
    s2 = wave_sum(s2);
    if ((threadIdx.x & 63) == 0) atomicAdd(accum, fmaf(s, sA, s2 * sC));
}

// edge loss + normal consistency fused (both independent of laplacian scatter)
__global__ void edge_nc_k(const float* __restrict__ pred,
                          const int* __restrict__ edges, int E,
                          const int* __restrict__ pairs, int P,
                          int N, int B, float scaleE, float scaleP,
                          float* __restrict__ accum)
{
    const int totalE = B * E;
    const int total  = totalE + B * P;
    float se = 0.f, sp = 0.f;
    for (int idx = blockIdx.x * blockDim.x + threadIdx.x; idx < total;
         idx += gridDim.x * blockDim.x) {
        if (idx < totalE) {
            const int b = idx / E;
            const int e = idx - b * E;
            const float* __restrict__ vb = pred + (size_t)b * N * 3;
            const int i0 = edges[e * 2 + 0], i1 = edges[e * 2 + 1];
            float dx = vb[i0 * 3 + 0] - vb[i1 * 3 + 0];
            float dy = vb[i0 * 3 + 1] - vb[i1 * 3 + 1];
            float dz = vb[i0 * 3 + 2] - vb[i1 * 3 + 2];
            se += fmaf(dx, dx, fmaf(dy, dy, dz * dz));
        } else {
            const int q = idx - totalE;
            const int b = q / P;
            const int p = q - b * P;
            const float* __restrict__ vb = pred + (size_t)b * N * 3;
            const int a0 = pairs[p * 4 + 0], a1 = pairs[p * 4 + 1];
            const int a2 = pairs[p * 4 + 2], a3 = pairs[p * 4 + 3];
            float p0x = vb[a0 * 3], p0y = vb[a0 * 3 + 1], p0z = vb[a0 * 3 + 2];
            float ex = vb[a1 * 3] - p0x, ey = vb[a1 * 3 + 1] - p0y, ez = vb[a1 * 3 + 2] - p0z;
            float ux = vb[a2 * 3] - p0x, uy = vb[a2 * 3 + 1] - p0y, uz = vb[a2 * 3 + 2] - p0z;
            float wx = vb[a3 * 3] - p0x, wy = vb[a3 * 3 + 1] - p0y, wz = vb[a3 * 3 + 2] - p0z;
            float n0x = ey * uz - ez * uy;
            float n0y = ez * ux - ex * uz;
            float n0z = ex * uy - ey * ux;
            float n1x = -(ey * wz - ez * wy);
            float n1y = -(ez * wx - ex * wz);
            float n1z = -(ex * wy - ey * wx);
            float dt = n0x * n1x + n0y * n1y + n0z * n1z;
            float l0 = sqrtf(n0x * n0x + n0y * n0y + n0z * n0z);
            float l1 = sqrtf(n1x * n1x + n1y * n1y + n1z * n1z);
            sp += 1.0f - dt / (fmaxf(l0, 1e-8f) * fmaxf(l1, 1e-8f));
        }
    }
    se = wave_sum(se);
    sp = wave_sum(sp);
    if ((threadIdx.x & 63) == 0) atomicAdd(accum, fmaf(se, scaleE, sp * scaleP));
}

__global__ void lap_scatter_k(const float* __restrict__ pred, const int* __restrict__ faces,
                              int F, int N, int B,
                              float* __restrict__ Lx, float* __restrict__ rowsum)
{
    const int total = B * F;
    for (int idx = blockIdx.x * blockDim.x + threadIdx.x; idx < total;
         idx += gridDim.x * blockDim.x) {
        const int b = idx / F;
        const int f = idx - b * F;
        const float* __restrict__ vb = pred + (size_t)b * N * 3;
        const int i0 = faces[f * 3 + 0], i1 = faces[f * 3 + 1], i2 = faces[f * 3 + 2];
        float v0x = vb[i0 * 3], v0y = vb[i0 * 3 + 1], v0z = vb[i0 * 3 + 2];
        float v1x = vb[i1 * 3], v1y = vb[i1 * 3 + 1], v1z = vb[i1 * 3 + 2];
        float v2x = vb[i2 * 3], v2y = vb[i2 * 3 + 1], v2z = vb[i2 * 3 + 2];
        float ax = v1x - v2x, ay = v1y - v2y, az = v1z - v2z;
        float bx = v0x - v2x, by = v0y - v2y, bz = v0z - v2z;
        float cx = v0x - v1x, cy = v0y - v1y, cz = v0z - v1z;
        float A  = sqrtf(ax * ax + ay * ay + az * az);
        float Bl = sqrtf(bx * bx + by * by + bz * bz);
        float C  = sqrtf(cx * cx + cy * cy + cz * cz);
        float sp = 0.5f * (A + Bl + C);
        float area = sqrtf(fmaxf(sp * (sp - A) * (sp - Bl) * (sp - C), 1e-12f));
        float A2 = A * A, B2 = Bl * Bl, C2 = C * C;
        float inv4a = 1.0f / (4.0f * area);
        float cota = (B2 + C2 - A2) * inv4a;
        float cotb = (A2 + C2 - B2) * inv4a;
        float cotc = (A2 + B2 - C2) * inv4a;

        float* __restrict__ Lb = Lx + (size_t)b * N * 3;
        float* __restrict__ rb = rowsum + (size_t)b * N;
        // cot[k] symmetric on edge (ii[k], jj[k]): cota<->(1,2), cotb<->(2,0), cotc<->(0,1)
        #define SCAT(i, j, w)                                             \
            atomicAdd(&Lb[(i) * 3 + 0], (w) * vb[(j) * 3 + 0]);           \
            atomicAdd(&Lb[(i) * 3 + 1], (w) * vb[(j) * 3 + 1]);           \
            atomicAdd(&Lb[(i) * 3 + 2], (w) * vb[(j) * 3 + 2]);           \
            atomicAdd(&rb[(i)], (w));
        SCAT(i1, i2, cota) SCAT(i2, i1, cota)
        SCAT(i2, i0, cotb) SCAT(i0, i2, cotb)
        SCAT(i0, i1, cotc) SCAT(i1, i0, cotc)
        #undef SCAT
    }
}

__global__ void lap_final_k(const float* __restrict__ pred, const float* __restrict__ Lx,
                            const float* __restrict__ rowsum, int N, int B, float scale,
                            float* __restrict__ accum)
{
    float s = 0.f;
    const int total = B * N;
    for (int idx = blockIdx.x * blockDim.x + threadIdx.x; idx < total;
         idx += gridDim.x * blockDim.x) {
        float rs = rowsum[idx];
        float nw = rs > 0.f ? 1.0f / rs : 0.f;
        float rx = Lx[idx * 3 + 0] * nw - pred[idx * 3 + 0];
        float ry = Lx[idx * 3 + 1] * nw - pred[idx * 3 + 1];
        float rz = Lx[idx * 3 + 2] * nw - pred[idx * 3 + 2];
        s += sqrtf(rx * rx + ry * ry + rz * rz);
    }
    s = wave_sum(s);
    if ((threadIdx.x & 63) == 0) atomicAdd(accum, s * scale);
}

__global__ void write_out_k(const float* __restrict__ accum, float* __restrict__ out)
{
    out[0] = accum[0];
}

extern "C" void kernel_launch(void* const* d_in, const int* in_sizes, int n_in,
                              void* d_out, int out_size, void* d_ws, size_t ws_size,
                              hipStream_t stream)
{
    const float* pred = (const float*)d_in[0];
    const float* tgt  = (const float*)d_in[1];
    const int* faces  = (const int*)d_in[2];
    const int* edges  = (const int*)d_in[3];
    const int* pairs  = (const int*)d_in[4];

    const int B = 2;
    const int N = in_sizes[0] / (3 * B);   // 8281
    const int F = in_sizes[2] / 3;         // 16200
    const int E = in_sizes[3] / 2;         // ~24480
    const int P = in_sizes[4] / 4;         // ~24120
    const int N1 = N - 1;

    // workspace layout (floats)
    float* ws       = (float*)d_ws;
    float* accum    = ws;                        // 8
    float* Lx       = ws + 8;                    // B*N*3
    float* rowsum   = Lx + (size_t)B * N * 3;    // B*N
    unsigned int* minA = (unsigned int*)(rowsum + (size_t)B * N); // B*N   pred->tgt
    unsigned int* minB = minA + (size_t)B * N;                    // B*N   tgt->pred
    unsigned int* minC = minB + (size_t)B * N;                    // B*N1  vel fwd
    unsigned int* minD = minC + (size_t)B * N1;                   // B*N1  vel bwd

    const size_t zero_bytes = (8 + (size_t)B * N * 3 + (size_t)B * N) * sizeof(float);
    const size_t inf_bytes  = (2 * (size_t)B * N + 2 * (size_t)B * N1) * sizeof(float);
    hipMemsetAsync(ws, 0, zero_bytes, stream);
    hipMemsetAsync(minA, 0x7F, inf_bytes, stream);  // 0x7F7F7F7F ~ 3.39e38 > any d

    const dim3 blk(256);
    const dim3 gc((N + 256 * NX - 1) / (256 * NX), NYCH, B);
    const dim3 gv((N1 + 256 * NX - 1) / (256 * NX), NYCH, B);
    chamfer_min_k<0><<<gc, blk, 0, stream>>>(pred, tgt, N, minA);
    chamfer_min_k<0><<<gc, blk, 0, stream>>>(tgt, pred, N, minB);
    chamfer_min_k<1><<<gv, blk, 0, stream>>>(pred, tgt, N, minC);
    chamfer_min_k<1><<<gv, blk, 0, stream>>>(tgt, pred, N, minD);

    const float sBN  = 1.0f / ((float)B * (float)N);
    const float sBN1 = W_VEL / ((float)B * (float)N1);
    reduce_mins_k<<<64, blk, 0, stream>>>(minA, 2 * B * N, 2 * B * N1, sBN, sBN1, accum);

    edge_nc_k<<<96, blk, 0, stream>>>(pred, edges, E, pairs, P, N, B,
                                      W_EDGE / ((float)B * (float)E),
                                      W_NORMAL / ((float)B * (float)P), accum);
    lap_scatter_k<<<128, blk, 0, stream>>>(pred, faces, F, N, B, Lx, rowsum);
    lap_final_k<<<65, blk, 0, stream>>>(pred, Lx, rowsum, N, B,
                                        W_LAP / ((float)B * (float)N), accum);

    write_out_k<<<1, 1, 0, stream>>>(accum, (float*)d_out);
}

// Round 3
// 97.212 us; speedup vs baseline: 5.2374x; 1.6650x over previous
//
#include <hip/hip_runtime.h>

// ---------------------------------------------------------------------------
// Chamfer_Loss: chamfer(pred,tgt) + W_EDGE*edge + W_LAP*cotLap + W_NORMAL*nc
//               + W_VEL*chamfer(diff(pred), diff(tgt))
// B=2, N=8281 (g=91), fp32 in/out. Output: 1 scalar.
// R3: kill hipMemsetAsync fills (init kernel), fuse all 4 chamfer passes into
//     one dispatch, 5-op inner loop (m=min(yy-2x.y), +xx and clamp at end),
//     float4 LDS staging (broadcast ds_read_b128).
// ---------------------------------------------------------------------------

#define W_EDGE   0.5f
#define W_LAP    0.05f
#define W_NORMAL 0.01f
#define W_VEL    10.0f

#define NX 8          // x points per thread (registers)
#define NYCH 52       // y chunks (grid.y)

__device__ __forceinline__ float wave_sum(float v) {
#pragma unroll
    for (int o = 32; o > 0; o >>= 1) v += __shfl_down(v, o, 64);
    return v;
}

// Zero [accum | Lx | rowsum] and set the 4 min arrays to +big.
__global__ void init_ws_k(float* __restrict__ ws, int nzero, int ninf)
{
    unsigned int* w = (unsigned int*)ws;
    const int total = nzero + ninf;
    for (int i = blockIdx.x * blockDim.x + threadIdx.x; i < total;
         i += gridDim.x * blockDim.x)
        w[i] = (i < nzero) ? 0u : 0x7F7F7F7Fu;   // 3.39e38f
}

// All 4 chamfer direction/shift/batch combos in one dispatch.
// blockIdx.z = variant*2 + b, variant: 0 pred->tgt, 1 tgt->pred,
//                                      2 dpred->dtgt, 3 dtgt->dpred.
// mins layout: [B*N minA][B*N minB][B*N1 minC][B*N1 minD]
__global__ __launch_bounds__(256)
void chamfer_all_k(const float* __restrict__ pred, const float* __restrict__ tgt,
                   int N, unsigned int* __restrict__ mins)
{
    const int variant = blockIdx.z >> 1;
    const int b       = blockIdx.z & 1;
    const int shift   = variant >> 1;
    const int Np      = N - shift;

    const float* __restrict__ xb = ((variant & 1) == 0 ? pred : tgt) + (size_t)b * N * 3;
    const float* __restrict__ yb = ((variant & 1) == 0 ? tgt : pred) + (size_t)b * N * 3;

    unsigned int* __restrict__ out;
    {
        const int N1 = N - 1;
        size_t off;
        if (variant == 0)      off = (size_t)b * N;
        else if (variant == 1) off = (size_t)2 * N + (size_t)b * N;      // B=2
        else if (variant == 2) off = (size_t)4 * N + (size_t)b * N1;
        else                   off = (size_t)4 * N + (size_t)2 * N1 + (size_t)b * N1;
        out = mins + off;
    }

    const int base = blockIdx.x * (256 * NX) + threadIdx.x;

    float xs0[NX], xs1[NX], xs2[NX], xx[NX], m[NX];
#pragma unroll
    for (int k = 0; k < NX; ++k) {
        const int gi = base + k * 256;
        m[k] = 3.0e38f;
        float a0 = 0.f, a1 = 0.f, a2 = 0.f;
        if (gi < Np) {
            if (shift) {
                a0 = xb[(gi + 1) * 3 + 0] - xb[gi * 3 + 0];
                a1 = xb[(gi + 1) * 3 + 1] - xb[gi * 3 + 1];
                a2 = xb[(gi + 1) * 3 + 2] - xb[gi * 3 + 2];
            } else {
                a0 = xb[gi * 3 + 0]; a1 = xb[gi * 3 + 1]; a2 = xb[gi * 3 + 2];
            }
        }
        xs0[k] = a0; xs1[k] = a1; xs2[k] = a2;
        xx[k]  = fmaf(a0, a0, fmaf(a1, a1, a2 * a2));
    }

    // y-range handled by this block
    const int per = (Np + gridDim.y - 1) / gridDim.y;
    const int ys  = blockIdx.y * per;
    const int ye  = min(Np, ys + per);

    __shared__ float4 sy[256];

    for (int t = ys; t < ye; t += 256) {
        const int cnt = min(256, ye - t);
        const int j = threadIdx.x;
        if (j < cnt) {
            const int yi = t + j;
            float y0, y1, y2;
            if (shift) {
                y0 = yb[(yi + 1) * 3 + 0] - yb[yi * 3 + 0];
                y1 = yb[(yi + 1) * 3 + 1] - yb[yi * 3 + 1];
                y2 = yb[(yi + 1) * 3 + 2] - yb[yi * 3 + 2];
            } else {
                y0 = yb[yi * 3 + 0]; y1 = yb[yi * 3 + 1]; y2 = yb[yi * 3 + 2];
            }
            const float yy = fmaf(y0, y0, fmaf(y1, y1, y2 * y2));
            sy[j] = make_float4(y0, y1, y2, yy);
        }
        __syncthreads();
#pragma unroll 4
        for (int jj = 0; jj < cnt; ++jj) {
            const float4 y = sy[jj];
#pragma unroll
            for (int k = 0; k < NX; ++k) {
                float dot = xs0[k] * y.x;
                dot = fmaf(xs1[k], y.y, dot);
                dot = fmaf(xs2[k], y.z, dot);
                m[k] = fminf(m[k], fmaf(-2.0f, dot, y.w));   // yy - 2 x.y
            }
        }
        __syncthreads();
    }
#pragma unroll
    for (int k = 0; k < NX; ++k) {
        const int gi = base + k * 256;
        if (gi < Np) {
            const float d = fmaxf(xx[k] + m[k], 0.0f);       // clamp like reference
            atomicMin(&out[gi], __float_as_uint(d));
        }
    }
}

// Sum all four min arrays (contiguous: [lenN2 @ sA][lenN12 @ sC]).
__global__ void reduce_mins_k(const unsigned int* __restrict__ mins, int lenN2, int lenN12,
                              float sA, float sC, float* __restrict__ accum)
{
    const int total = lenN2 + lenN12;
    float s = 0.f, s2 = 0.f;
    for (int i = blockIdx.x * blockDim.x + threadIdx.x; i < total;
         i += gridDim.x * blockDim.x) {
        const float v = __uint_as_float(mins[i]);
        if (i < lenN2) s += v; else s2 += v;
    }
    s  = wave_sum(s);
    s2 = wave_sum(s2);
    if ((threadIdx.x & 63) == 0) atomicAdd(accum, fmaf(s, sA, s2 * sC));
}

// edge loss + normal consistency fused
__global__ void edge_nc_k(const float* __restrict__ pred,
                          const int* __restrict__ edges, int E,
                          const int* __restrict__ pairs, int P,
                          int N, int B, float scaleE, float scaleP,
                          float* __restrict__ accum)
{
    const int totalE = B * E;
    const int total  = totalE + B * P;
    float se = 0.f, sp = 0.f;
    for (int idx = blockIdx.x * blockDim.x + threadIdx.x; idx < total;
         idx += gridDim.x * blockDim.x) {
        if (idx < totalE) {
            const int b = idx / E;
            const int e = idx - b * E;
            const float* __restrict__ vb = pred + (size_t)b * N * 3;
            const int i0 = edges[e * 2 + 0], i1 = edges[e * 2 + 1];
            float dx = vb[i0 * 3 + 0] - vb[i1 * 3 + 0];
            float dy = vb[i0 * 3 + 1] - vb[i1 * 3 + 1];
            float dz = vb[i0 * 3 + 2] - vb[i1 * 3 + 2];
            se += fmaf(dx, dx, fmaf(dy, dy, dz * dz));
        } else {
            const int q = idx - totalE;
            const int b = q / P;
            const int p = q - b * P;
            const float* __restrict__ vb = pred + (size_t)b * N * 3;
            const int a0 = pairs[p * 4 + 0], a1 = pairs[p * 4 + 1];
            const int a2 = pairs[p * 4 + 2], a3 = pairs[p * 4 + 3];
            float p0x = vb[a0 * 3], p0y = vb[a0 * 3 + 1], p0z = vb[a0 * 3 + 2];
            float ex = vb[a1 * 3] - p0x, ey = vb[a1 * 3 + 1] - p0y, ez = vb[a1 * 3 + 2] - p0z;
            float ux = vb[a2 * 3] - p0x, uy = vb[a2 * 3 + 1] - p0y, uz = vb[a2 * 3 + 2] - p0z;
            float wx = vb[a3 * 3] - p0x, wy = vb[a3 * 3 + 1] - p0y, wz = vb[a3 * 3 + 2] - p0z;
            float n0x = ey * uz - ez * uy;
            float n0y = ez * ux - ex * uz;
            float n0z = ex * uy - ey * ux;
            float n1x = -(ey * wz - ez * wy);
            float n1y = -(ez * wx - ex * wz);
            float n1z = -(ex * wy - ey * wx);
            float dt = n0x * n1x + n0y * n1y + n0z * n1z;
            float l0 = sqrtf(n0x * n0x + n0y * n0y + n0z * n0z);
            float l1 = sqrtf(n1x * n1x + n1y * n1y + n1z * n1z);
            sp += 1.0f - dt / (fmaxf(l0, 1e-8f) * fmaxf(l1, 1e-8f));
        }
    }
    se = wave_sum(se);
    sp = wave_sum(sp);
    if ((threadIdx.x & 63) == 0) atomicAdd(accum, fmaf(se, scaleE, sp * scaleP));
}

__global__ void lap_scatter_k(const float* __restrict__ pred, const int* __restrict__ faces,
                              int F, int N, int B,
                              float* __restrict__ Lx, float* __restrict__ rowsum)
{
    const int total = B * F;
    for (int idx = blockIdx.x * blockDim.x + threadIdx.x; idx < total;
         idx += gridDim.x * blockDim.x) {
        const int b = idx / F;
        const int f = idx - b * F;
        const float* __restrict__ vb = pred + (size_t)b * N * 3;
        const int i0 = faces[f * 3 + 0], i1 = faces[f * 3 + 1], i2 = faces[f * 3 + 2];
        float v0x = vb[i0 * 3], v0y = vb[i0 * 3 + 1], v0z = vb[i0 * 3 + 2];
        float v1x = vb[i1 * 3], v1y = vb[i1 * 3 + 1], v1z = vb[i1 * 3 + 2];
        float v2x = vb[i2 * 3], v2y = vb[i2 * 3 + 1], v2z = vb[i2 * 3 + 2];
        float ax = v1x - v2x, ay = v1y - v2y, az = v1z - v2z;
        float bx = v0x - v2x, by = v0y - v2y, bz = v0z - v2z;
        float cx = v0x - v1x, cy = v0y - v1y, cz = v0z - v1z;
        float A  = sqrtf(ax * ax + ay * ay + az * az);
        float Bl = sqrtf(bx * bx + by * by + bz * bz);
        float C  = sqrtf(cx * cx + cy * cy + cz * cz);
        float sp = 0.5f * (A + Bl + C);
        float area = sqrtf(fmaxf(sp * (sp - A) * (sp - Bl) * (sp - C), 1e-12f));
        float A2 = A * A, B2 = Bl * Bl, C2 = C * C;
        float inv4a = 1.0f / (4.0f * area);
        float cota = (B2 + C2 - A2) * inv4a;
        float cotb = (A2 + C2 - B2) * inv4a;
        float cotc = (A2 + B2 - C2) * inv4a;

        float* __restrict__ Lb = Lx + (size_t)b * N * 3;
        float* __restrict__ rb = rowsum + (size_t)b * N;
        // cot[k] symmetric on edge (ii[k], jj[k]): cota<->(1,2), cotb<->(2,0), cotc<->(0,1)
        #define SCAT(i, j, w)                                             \
            atomicAdd(&Lb[(i) * 3 + 0], (w) * vb[(j) * 3 + 0]);           \
            atomicAdd(&Lb[(i) * 3 + 1], (w) * vb[(j) * 3 + 1]);           \
            atomicAdd(&Lb[(i) * 3 + 2], (w) * vb[(j) * 3 + 2]);           \
            atomicAdd(&rb[(i)], (w));
        SCAT(i1, i2, cota) SCAT(i2, i1, cota)
        SCAT(i2, i0, cotb) SCAT(i0, i2, cotb)
        SCAT(i0, i1, cotc) SCAT(i1, i0, cotc)
        #undef SCAT
    }
}

__global__ void lap_final_k(const float* __restrict__ pred, const float* __restrict__ Lx,
                            const float* __restrict__ rowsum, int N, int B, float scale,
                            float* __restrict__ accum)
{
    float s = 0.f;
    const int total = B * N;
    for (int idx = blockIdx.x * blockDim.x + threadIdx.x; idx < total;
         idx += gridDim.x * blockDim.x) {
        float rs = rowsum[idx];
        float nw = rs > 0.f ? 1.0f / rs : 0.f;
        float rx = Lx[idx * 3 + 0] * nw - pred[idx * 3 + 0];
        float ry = Lx[idx * 3 + 1] * nw - pred[idx * 3 + 1];
        float rz = Lx[idx * 3 + 2] * nw - pred[idx * 3 + 2];
        s += sqrtf(rx * rx + ry * ry + rz * rz);
    }
    s = wave_sum(s);
    if ((threadIdx.x & 63) == 0) atomicAdd(accum, s * scale);
}

__global__ void write_out_k(const float* __restrict__ accum, float* __restrict__ out)
{
    out[0] = accum[0];
}

extern "C" void kernel_launch(void* const* d_in, const int* in_sizes, int n_in,
                              void* d_out, int out_size, void* d_ws, size_t ws_size,
                              hipStream_t stream)
{
    const float* pred = (const float*)d_in[0];
    const float* tgt  = (const float*)d_in[1];
    const int* faces  = (const int*)d_in[2];
    const int* edges  = (const int*)d_in[3];
    const int* pairs  = (const int*)d_in[4];

    const int B = 2;
    const int N = in_sizes[0] / (3 * B);   // 8281
    const int F = in_sizes[2] / 3;         // 16200
    const int E = in_sizes[3] / 2;         // ~24480
    const int P = in_sizes[4] / 4;         // ~24120
    const int N1 = N - 1;

    // workspace layout (floats)
    float* ws       = (float*)d_ws;
    float* accum    = ws;                        // 8
    float* Lx       = ws + 8;                    // B*N*3
    float* rowsum   = Lx + (size_t)B * N * 3;    // B*N
    unsigned int* minsBase = (unsigned int*)(rowsum + (size_t)B * N); // 2*B*N + 2*B*N1

    const int nzero = 8 + B * N * 3 + B * N;
    const int ninf  = 2 * B * N + 2 * B * N1;

    const dim3 blk(256);
    init_ws_k<<<64, blk, 0, stream>>>(ws, nzero, ninf);

    const dim3 gc((N + 256 * NX - 1) / (256 * NX), NYCH, 4 * B);
    chamfer_all_k<<<gc, blk, 0, stream>>>(pred, tgt, N, minsBase);

    const float sBN  = 1.0f / ((float)B * (float)N);
    const float sBN1 = W_VEL / ((float)B * (float)N1);
    reduce_mins_k<<<64, blk, 0, stream>>>(minsBase, 2 * B * N, 2 * B * N1, sBN, sBN1, accum);

    edge_nc_k<<<96, blk, 0, stream>>>(pred, edges, E, pairs, P, N, B,
                                      W_EDGE / ((float)B * (float)E),
                                      W_NORMAL / ((float)B * (float)P), accum);
    lap_scatter_k<<<128, blk, 0, stream>>>(pred, faces, F, N, B, Lx, rowsum);
    lap_final_k<<<65, blk, 0, stream>>>(pred, Lx, rowsum, N, B,
                                        W_LAP / ((float)B * (float)N), accum);

    write_out_k<<<1, 1, 0, stream>>>(accum, (float*)d_out);
}

// Round 4
// 82.404 us; speedup vs baseline: 6.1786x; 1.1797x over previous
//
#include <hip/hip_runtime.h>

// ---------------------------------------------------------------------------
// Chamfer_Loss: chamfer(pred,tgt) + W_EDGE*edge + W_LAP*cotLap + W_NORMAL*nc
//               + W_VEL*chamfer(diff(pred), diff(tgt))
// B=2, N=8281 (g=91), fp32 in/out. Output: 1 scalar.
// R4: 4-op chamfer eval (pre-scaled -2x, yy folded into fma chain start),
//     compile-time 256-y tile (padded, no inner branches), NX=7/TPB=128 for
//     less x-padding + balance; kernel fusion: mesh_k (edge+nc+scatter),
//     finalize_k (mins reduce + lap residual).
// ---------------------------------------------------------------------------

#define W_EDGE   0.5f
#define W_LAP    0.05f
#define W_NORMAL 0.01f
#define W_VEL    10.0f

#define NX  7          // x points per thread (registers)
#define TPB 128        // threads per chamfer block
#define YT  256        // y tile size (compile-time inner trip count)

__device__ __forceinline__ float wave_sum(float v) {
#pragma unroll
    for (int o = 32; o > 0; o >>= 1) v += __shfl_down(v, o, 64);
    return v;
}

// Zero [accum | Lx | rowsum] and set the 4 min arrays to +big.
__global__ void init_ws_k(float* __restrict__ ws, int nzero, int ninf)
{
    unsigned int* w = (unsigned int*)ws;
    const int total = nzero + ninf;
    for (int i = blockIdx.x * blockDim.x + threadIdx.x; i < total;
         i += gridDim.x * blockDim.x)
        w[i] = (i < nzero) ? 0u : 0x7F7F7F7Fu;   // 3.39e38f
}

// All 4 chamfer direction/shift/batch combos in one dispatch.
// blockIdx.z = variant*2 + b, variant: 0 pred->tgt, 1 tgt->pred,
//                                      2 dpred->dtgt, 3 dtgt->dpred.
// mins layout: [B*N minA][B*N minB][B*N1 minC][B*N1 minD]
// Each block: NX*TPB x-points (registers) vs one 256-y tile (LDS, padded).
__global__ __launch_bounds__(TPB)
void chamfer_all_k(const float* __restrict__ pred, const float* __restrict__ tgt,
                   int N, unsigned int* __restrict__ mins)
{
    const int variant = blockIdx.z >> 1;
    const int b       = blockIdx.z & 1;
    const int shift   = variant >> 1;
    const int Np      = N - shift;
    const int N1      = N - 1;

    const float* __restrict__ xb = ((variant & 1) == 0 ? pred : tgt) + (size_t)b * N * 3;
    const float* __restrict__ yb = ((variant & 1) == 0 ? tgt : pred) + (size_t)b * N * 3;

    size_t off;
    if (variant == 0)      off = (size_t)b * N;
    else if (variant == 1) off = (size_t)2 * N + (size_t)b * N;          // B=2
    else if (variant == 2) off = (size_t)4 * N + (size_t)b * N1;
    else                   off = (size_t)4 * N + (size_t)2 * N1 + (size_t)b * N1;
    unsigned int* __restrict__ out = mins + off;

    const int base = blockIdx.x * (TPB * NX) + threadIdx.x;

    float xs0[NX], xs1[NX], xs2[NX], xx[NX], m[NX];
#pragma unroll
    for (int k = 0; k < NX; ++k) {
        const int gi = base + k * TPB;
        float a0 = 0.f, a1 = 0.f, a2 = 0.f;
        if (gi < Np) {
            if (shift) {
                a0 = xb[(gi + 1) * 3 + 0] - xb[gi * 3 + 0];
                a1 = xb[(gi + 1) * 3 + 1] - xb[gi * 3 + 1];
                a2 = xb[(gi + 1) * 3 + 2] - xb[gi * 3 + 2];
            } else {
                a0 = xb[gi * 3 + 0]; a1 = xb[gi * 3 + 1]; a2 = xb[gi * 3 + 2];
            }
        }
        xx[k]  = fmaf(a0, a0, fmaf(a1, a1, a2 * a2));
        xs0[k] = -2.0f * a0; xs1[k] = -2.0f * a1; xs2[k] = -2.0f * a2;
        m[k]   = 3.0e38f;
    }

    // stage one 256-y tile; pad with yy=+big (min-neutral)
    __shared__ float4 sy[YT];
    const int ys = blockIdx.y * YT;
#pragma unroll
    for (int r = 0; r < YT / TPB; ++r) {
        const int j  = threadIdx.x + r * TPB;
        const int yi = ys + j;
        float4 v = make_float4(0.f, 0.f, 0.f, 3.0e38f);
        if (yi < Np) {
            float y0, y1, y2;
            if (shift) {
                y0 = yb[(yi + 1) * 3 + 0] - yb[yi * 3 + 0];
                y1 = yb[(yi + 1) * 3 + 1] - yb[yi * 3 + 1];
                y2 = yb[(yi + 1) * 3 + 2] - yb[yi * 3 + 2];
            } else {
                y0 = yb[yi * 3 + 0]; y1 = yb[yi * 3 + 1]; y2 = yb[yi * 3 + 2];
            }
            v = make_float4(y0, y1, y2, fmaf(y0, y0, fmaf(y1, y1, y2 * y2)));
        }
        sy[j] = v;
    }
    __syncthreads();

#pragma unroll 8
    for (int jj = 0; jj < YT; ++jj) {
        const float4 y = sy[jj];
#pragma unroll
        for (int k = 0; k < NX; ++k) {
            // u = yy - 2 x.y   (x pre-scaled by -2, yy folded into chain start)
            float u = fmaf(xs0[k], y.x, fmaf(xs1[k], y.y, fmaf(xs2[k], y.z, y.w)));
            m[k] = fminf(m[k], u);
        }
    }

#pragma unroll
    for (int k = 0; k < NX; ++k) {
        const int gi = base + k * TPB;
        if (gi < Np) {
            const float d = fmaxf(xx[k] + m[k], 0.0f);       // clamp like reference
            atomicMin(&out[gi], __float_as_uint(d));
        }
    }
}

// edge loss + normal consistency + laplacian cot scatter, one dispatch.
__global__ void mesh_k(const float* __restrict__ pred,
                       const int* __restrict__ edges, int E,
                       const int* __restrict__ pairs, int P,
                       const int* __restrict__ faces, int F,
                       int N, int B, float scaleE, float scaleP,
                       float* __restrict__ Lx, float* __restrict__ rowsum,
                       float* __restrict__ accum)
{
    const int tE = B * E, tP = B * P, tF = B * F;
    const int total = tE + tP + tF;
    float se = 0.f, sp = 0.f;
    for (int idx = blockIdx.x * blockDim.x + threadIdx.x; idx < total;
         idx += gridDim.x * blockDim.x) {
        if (idx < tE) {
            const int b = idx / E;
            const int e = idx - b * E;
            const float* __restrict__ vb = pred + (size_t)b * N * 3;
            const int i0 = edges[e * 2 + 0], i1 = edges[e * 2 + 1];
            float dx = vb[i0 * 3 + 0] - vb[i1 * 3 + 0];
            float dy = vb[i0 * 3 + 1] - vb[i1 * 3 + 1];
            float dz = vb[i0 * 3 + 2] - vb[i1 * 3 + 2];
            se += fmaf(dx, dx, fmaf(dy, dy, dz * dz));
        } else if (idx < tE + tP) {
            const int q = idx - tE;
            const int b = q / P;
            const int p = q - b * P;
            const float* __restrict__ vb = pred + (size_t)b * N * 3;
            const int a0 = pairs[p * 4 + 0], a1 = pairs[p * 4 + 1];
            const int a2 = pairs[p * 4 + 2], a3 = pairs[p * 4 + 3];
            float p0x = vb[a0 * 3], p0y = vb[a0 * 3 + 1], p0z = vb[a0 * 3 + 2];
            float ex = vb[a1 * 3] - p0x, ey = vb[a1 * 3 + 1] - p0y, ez = vb[a1 * 3 + 2] - p0z;
            float ux = vb[a2 * 3] - p0x, uy = vb[a2 * 3 + 1] - p0y, uz = vb[a2 * 3 + 2] - p0z;
            float wx = vb[a3 * 3] - p0x, wy = vb[a3 * 3 + 1] - p0y, wz = vb[a3 * 3 + 2] - p0z;
            float n0x = ey * uz - ez * uy;
            float n0y = ez * ux - ex * uz;
            float n0z = ex * uy - ey * ux;
            float n1x = -(ey * wz - ez * wy);
            float n1y = -(ez * wx - ex * wz);
            float n1z = -(ex * wy - ey * wx);
            float dt = n0x * n1x + n0y * n1y + n0z * n1z;
            float l0 = sqrtf(n0x * n0x + n0y * n0y + n0z * n0z);
            float l1 = sqrtf(n1x * n1x + n1y * n1y + n1z * n1z);
            sp += 1.0f - dt / (fmaxf(l0, 1e-8f) * fmaxf(l1, 1e-8f));
        } else {
            const int q = idx - tE - tP;
            const int b = q / F;
            const int f = q - b * F;
            const float* __restrict__ vb = pred + (size_t)b * N * 3;
            const int i0 = faces[f * 3 + 0], i1 = faces[f * 3 + 1], i2 = faces[f * 3 + 2];
            float v0x = vb[i0 * 3], v0y = vb[i0 * 3 + 1], v0z = vb[i0 * 3 + 2];
            float v1x = vb[i1 * 3], v1y = vb[i1 * 3 + 1], v1z = vb[i1 * 3 + 2];
            float v2x = vb[i2 * 3], v2y = vb[i2 * 3 + 1], v2z = vb[i2 * 3 + 2];
            float ax = v1x - v2x, ay = v1y - v2y, az = v1z - v2z;
            float bx = v0x - v2x, by = v0y - v2y, bz = v0z - v2z;
            float cx = v0x - v1x, cy = v0y - v1y, cz = v0z - v1z;
            float A  = sqrtf(ax * ax + ay * ay + az * az);
            float Bl = sqrtf(bx * bx + by * by + bz * bz);
            float C  = sqrtf(cx * cx + cy * cy + cz * cz);
            float s2 = 0.5f * (A + Bl + C);
            float area = sqrtf(fmaxf(s2 * (s2 - A) * (s2 - Bl) * (s2 - C), 1e-12f));
            float A2 = A * A, B2 = Bl * Bl, C2 = C * C;
            float inv4a = 1.0f / (4.0f * area);
            float cota = (B2 + C2 - A2) * inv4a;
            float cotb = (A2 + C2 - B2) * inv4a;
            float cotc = (A2 + B2 - C2) * inv4a;

            float* __restrict__ Lb = Lx + (size_t)b * N * 3;
            float* __restrict__ rb = rowsum + (size_t)b * N;
            // cot[k] symmetric on edge (ii[k],jj[k]): cota<->(1,2) cotb<->(2,0) cotc<->(0,1)
            #define SCAT(i, j, w)                                             \
                atomicAdd(&Lb[(i) * 3 + 0], (w) * vb[(j) * 3 + 0]);           \
                atomicAdd(&Lb[(i) * 3 + 1], (w) * vb[(j) * 3 + 1]);           \
                atomicAdd(&Lb[(i) * 3 + 2], (w) * vb[(j) * 3 + 2]);           \
                atomicAdd(&rb[(i)], (w));
            SCAT(i1, i2, cota) SCAT(i2, i1, cota)
            SCAT(i2, i0, cotb) SCAT(i0, i2, cotb)
            SCAT(i0, i1, cotc) SCAT(i1, i0, cotc)
            #undef SCAT
        }
    }
    se = wave_sum(se);
    sp = wave_sum(sp);
    if ((threadIdx.x & 63) == 0) atomicAdd(accum, fmaf(se, scaleE, sp * scaleP));
}

// chamfer mins reduction + laplacian residual norm, one dispatch.
__global__ void finalize_k(const unsigned int* __restrict__ mins, int lenN2, int lenN12,
                           float sA, float sC,
                           const float* __restrict__ pred, const float* __restrict__ Lx,
                           const float* __restrict__ rowsum, int N, int B, float scaleL,
                           float* __restrict__ accum)
{
    const int tM = lenN2 + lenN12;
    const int total = tM + B * N;
    float s1 = 0.f, s2 = 0.f, s3 = 0.f;
    for (int idx = blockIdx.x * blockDim.x + threadIdx.x; idx < total;
         idx += gridDim.x * blockDim.x) {
        if (idx < lenN2)      s1 += __uint_as_float(mins[idx]);
        else if (idx < tM)    s2 += __uint_as_float(mins[idx]);
        else {
            const int q = idx - tM;
            float rs = rowsum[q];
            float nw = rs > 0.f ? 1.0f / rs : 0.f;
            float rx = Lx[q * 3 + 0] * nw - pred[q * 3 + 0];
            float ry = Lx[q * 3 + 1] * nw - pred[q * 3 + 1];
            float rz = Lx[q * 3 + 2] * nw - pred[q * 3 + 2];
            s3 += sqrtf(rx * rx + ry * ry + rz * rz);
        }
    }
    s1 = wave_sum(s1);
    s2 = wave_sum(s2);
    s3 = wave_sum(s3);
    if ((threadIdx.x & 63) == 0)
        atomicAdd(accum, fmaf(s1, sA, fmaf(s2, sC, s3 * scaleL)));
}

__global__ void write_out_k(const float* __restrict__ accum, float* __restrict__ out)
{
    out[0] = accum[0];
}

extern "C" void kernel_launch(void* const* d_in, const int* in_sizes, int n_in,
                              void* d_out, int out_size, void* d_ws, size_t ws_size,
                              hipStream_t stream)
{
    const float* pred = (const float*)d_in[0];
    const float* tgt  = (const float*)d_in[1];
    const int* faces  = (const int*)d_in[2];
    const int* edges  = (const int*)d_in[3];
    const int* pairs  = (const int*)d_in[4];

    const int B = 2;
    const int N = in_sizes[0] / (3 * B);   // 8281
    const int F = in_sizes[2] / 3;         // 16200
    const int E = in_sizes[3] / 2;         // ~24480
    const int P = in_sizes[4] / 4;         // ~24120
    const int N1 = N - 1;

    // workspace layout (floats)
    float* ws       = (float*)d_ws;
    float* accum    = ws;                        // 8
    float* Lx       = ws + 8;                    // B*N*3
    float* rowsum   = Lx + (size_t)B * N * 3;    // B*N
    unsigned int* minsBase = (unsigned int*)(rowsum + (size_t)B * N); // 2*B*N + 2*B*N1

    const int nzero = 8 + B * N * 3 + B * N;
    const int ninf  = 2 * B * N + 2 * B * N1;

    init_ws_k<<<64, dim3(256), 0, stream>>>(ws, nzero, ninf);

    const dim3 gc((N + TPB * NX - 1) / (TPB * NX), (N + YT - 1) / YT, 4 * B);
    chamfer_all_k<<<gc, dim3(TPB), 0, stream>>>(pred, tgt, N, minsBase);

    mesh_k<<<128, dim3(256), 0, stream>>>(pred, edges, E, pairs, P, faces, F, N, B,
                                          W_EDGE / ((float)B * (float)E),
                                          W_NORMAL / ((float)B * (float)P),
                                          Lx, rowsum, accum);

    const float sBN  = 1.0f / ((float)B * (float)N);
    const float sBN1 = W_VEL / ((float)B * (float)N1);
    finalize_k<<<96, dim3(256), 0, stream>>>(minsBase, 2 * B * N, 2 * B * N1, sBN, sBN1,
                                             pred, Lx, rowsum, N, B,
                                             W_LAP / ((float)B * (float)N), accum);

    write_out_k<<<1, 1, 0, stream>>>(accum, (float*)d_out);
}